// Round 2
// baseline (6720.873 us; speedup 1.0000x reference)
//
#include <hip/hip_runtime.h>
#include <math.h>

// Problem constants
#define BB 8
#define SQL 2048
#define SKL 2048
#define DD 1024

// SGEMM tiling
#define BM 128
#define BN 128
#define BK 8
#define TM 8
#define TN 8
// 256 threads = (BM/TM)*(BN/TN)

// C = A @ B (+bias) (+tanh).  A:[M,K] row-major, B:[K,N] row-major.
__global__ __launch_bounds__(256, 2)
void sgemm_nn(const float* __restrict__ A, const float* __restrict__ B,
              const float* __restrict__ bias, float* __restrict__ C,
              int N, int K, int do_tanh)
{
    __shared__ float As[BK][BM];   // transposed A tile
    __shared__ float Bs[BK][BN];

    const int tid = threadIdx.x;
    const int tx = tid & 15, ty = tid >> 4;
    const int row0 = blockIdx.y * BM, col0 = blockIdx.x * BN;

    // A-tile load: 128 rows x 8 cols; 2 threads/row, one float4 each
    const int arow = tid >> 1;
    const int acol = (tid & 1) * 4;
    // B-tile load: 8 rows x 128 cols; one float4 each
    const int brow = tid >> 5;
    const int bcol = (tid & 31) * 4;

    float acc[TM][TN];
#pragma unroll
    for (int i = 0; i < TM; i++)
#pragma unroll
        for (int j = 0; j < TN; j++) acc[i][j] = 0.f;

    for (int k0 = 0; k0 < K; k0 += BK) {
        float4 av = *(const float4*)(A + (long)(row0 + arow) * K + k0 + acol);
        float4 bv = *(const float4*)(B + (long)(k0 + brow) * N + col0 + bcol);
        As[acol + 0][arow] = av.x;
        As[acol + 1][arow] = av.y;
        As[acol + 2][arow] = av.z;
        As[acol + 3][arow] = av.w;
        *(float4*)(&Bs[brow][bcol]) = bv;
        __syncthreads();
#pragma unroll
        for (int kk = 0; kk < BK; kk++) {
            float a[TM], bb[TN];
#pragma unroll
            for (int i = 0; i < TM; i++) a[i] = As[kk][ty * TM + i];
#pragma unroll
            for (int j = 0; j < TN; j++) bb[j] = Bs[kk][tx * TN + j];
#pragma unroll
            for (int i = 0; i < TM; i++)
#pragma unroll
                for (int j = 0; j < TN; j++) acc[i][j] += a[i] * bb[j];
        }
        __syncthreads();
    }

#pragma unroll
    for (int i = 0; i < TM; i++) {
        const int r = row0 + ty * TM + i;
#pragma unroll
        for (int j = 0; j < TN; j += 4) {
            const int c = col0 + tx * TN + j;
            float4 v;
            v.x = acc[i][j + 0]; v.y = acc[i][j + 1];
            v.z = acc[i][j + 2]; v.w = acc[i][j + 3];
            if (bias) {
                v.x += bias[c]; v.y += bias[c + 1];
                v.z += bias[c + 2]; v.w += bias[c + 3];
            }
            if (do_tanh) {
                v.x = tanhf(v.x); v.y = tanhf(v.y);
                v.z = tanhf(v.z); v.w = tanhf(v.w);
            }
            *(float4*)(C + (long)r * N + c) = v;
        }
    }
}

// C = A @ B^T + mask[col].  A:[M,K], B:[N,K] both row-major (dot of rows).
__global__ __launch_bounds__(256, 2)
void sgemm_nt_mask(const float* __restrict__ A, const float* __restrict__ B,
                   const int* __restrict__ mask, float* __restrict__ C,
                   int K, int Ncols)
{
    __shared__ float As[BK][BM];
    __shared__ float Bs[BK][BN];

    const int tid = threadIdx.x;
    const int tx = tid & 15, ty = tid >> 4;
    const int row0 = blockIdx.y * BM, col0 = blockIdx.x * BN;

    const int arow = tid >> 1;
    const int acol = (tid & 1) * 4;

    float acc[TM][TN];
#pragma unroll
    for (int i = 0; i < TM; i++)
#pragma unroll
        for (int j = 0; j < TN; j++) acc[i][j] = 0.f;

    for (int k0 = 0; k0 < K; k0 += BK) {
        float4 av = *(const float4*)(A + (long)(row0 + arow) * K + k0 + acol);
        float4 bv = *(const float4*)(B + (long)(col0 + arow) * K + k0 + acol);
        As[acol + 0][arow] = av.x;
        As[acol + 1][arow] = av.y;
        As[acol + 2][arow] = av.z;
        As[acol + 3][arow] = av.w;
        Bs[acol + 0][arow] = bv.x;
        Bs[acol + 1][arow] = bv.y;
        Bs[acol + 2][arow] = bv.z;
        Bs[acol + 3][arow] = bv.w;
        __syncthreads();
#pragma unroll
        for (int kk = 0; kk < BK; kk++) {
            float a[TM], bb[TN];
#pragma unroll
            for (int i = 0; i < TM; i++) a[i] = As[kk][ty * TM + i];
#pragma unroll
            for (int j = 0; j < TN; j++) bb[j] = Bs[kk][tx * TN + j];
#pragma unroll
            for (int i = 0; i < TM; i++)
#pragma unroll
                for (int j = 0; j < TN; j++) acc[i][j] += a[i] * bb[j];
        }
        __syncthreads();
    }

#pragma unroll
    for (int i = 0; i < TM; i++) {
        const int r = row0 + ty * TM + i;
#pragma unroll
        for (int j = 0; j < TN; j += 4) {
            const int c = col0 + tx * TN + j;
            float4 v;
            v.x = acc[i][j + 0] + (float)mask[c + 0];
            v.y = acc[i][j + 1] + (float)mask[c + 1];
            v.z = acc[i][j + 2] + (float)mask[c + 2];
            v.w = acc[i][j + 3] + (float)mask[c + 3];
            *(float4*)(C + (long)r * Ncols + c) = v;
        }
    }
}

// In-place row softmax over rows of length N=2048. One block (256 thr) per row.
__global__ __launch_bounds__(256)
void softmax_rows(float* __restrict__ S, int N)
{
    float* p = S + (long)blockIdx.x * N;
    const int tid = threadIdx.x;
    const int w = tid >> 6, lane = tid & 63;

    float4 v0 = *(float4*)(p + tid * 8);
    float4 v1 = *(float4*)(p + tid * 8 + 4);

    float m = fmaxf(fmaxf(fmaxf(v0.x, v0.y), fmaxf(v0.z, v0.w)),
                    fmaxf(fmaxf(v1.x, v1.y), fmaxf(v1.z, v1.w)));
#pragma unroll
    for (int off = 32; off; off >>= 1) m = fmaxf(m, __shfl_down(m, off));

    __shared__ float wm[4];
    __shared__ float ws[4];
    if (lane == 0) wm[w] = m;
    __syncthreads();
    const float bm = fmaxf(fmaxf(wm[0], wm[1]), fmaxf(wm[2], wm[3]));

    v0.x = __expf(v0.x - bm); v0.y = __expf(v0.y - bm);
    v0.z = __expf(v0.z - bm); v0.w = __expf(v0.w - bm);
    v1.x = __expf(v1.x - bm); v1.y = __expf(v1.y - bm);
    v1.z = __expf(v1.z - bm); v1.w = __expf(v1.w - bm);

    float s = v0.x + v0.y + v0.z + v0.w + v1.x + v1.y + v1.z + v1.w;
#pragma unroll
    for (int off = 32; off; off >>= 1) s += __shfl_down(s, off);
    if (lane == 0) ws[w] = s;
    __syncthreads();
    const float inv = 1.f / (ws[0] + ws[1] + ws[2] + ws[3]);

    v0.x *= inv; v0.y *= inv; v0.z *= inv; v0.w *= inv;
    v1.x *= inv; v1.y *= inv; v1.z *= inv; v1.w *= inv;
    *(float4*)(p + tid * 8) = v0;
    *(float4*)(p + tid * 8 + 4) = v1;
}

extern "C" void kernel_launch(void* const* d_in, const int* in_sizes, int n_in,
                              void* d_out, int out_size, void* d_ws, size_t ws_size,
                              hipStream_t stream)
{
    const float* q    = (const float*)d_in[0];
    const float* k    = (const float*)d_in[1];
    const float* v    = (const float*)d_in[2];
    const int*   mask = (const int*)d_in[3];
    const float* Wq   = (const float*)d_in[4];
    const float* bq   = (const float*)d_in[5];
    const float* Wk   = (const float*)d_in[6];
    const float* bk   = (const float*)d_in[7];
    const float* Wv   = (const float*)d_in[8];
    const float* bv   = (const float*)d_in[9];
    float* out = (float*)d_out;

    // Qp (all batches) lives in d_out; overwritten by PV only after use.
    float* Qp  = out;
    // Workspace: per-batch buffers only (33.6 MB total).
    float* Kpb = (float*)d_ws;                      // [SK, DH]  8.4 MB
    float* Vpb = Kpb + (long)SKL * DD;              // [SK, DV]  8.4 MB
    float* Sb  = Vpb + (long)SKL * DD;              // [SQ, SK] 16.8 MB

    const dim3 blk(256);

    // Q projection for ALL batches at once: [B*SQ, D] @ [D, D] -> d_out
    const dim3 gq_all(DD / BN, (BB * SQL) / BM, 1);
    sgemm_nn<<<gq_all, blk, 0, stream>>>(q, Wq, bq, Qp, DD, DD, 0);

    const dim3 gp(DD / BN, SKL / BM, 1);       // per-batch projection grid
    const dim3 gs(SKL / BN, SQL / BM, 1);      // per-batch scores grid
    const dim3 gv(DD / BN, SQL / BM, 1);       // per-batch PV grid

    for (int b = 0; b < BB; b++) {
        const float* kb = k + (long)b * SKL * DD;
        const float* vb = v + (long)b * SKL * DD;
        const float* Qpb = Qp + (long)b * SQL * DD;
        float* outb = out + (long)b * SQL * DD;
        const int* mb = mask + (long)b * SKL;

        // K / V projections for this batch
        sgemm_nn<<<gp, blk, 0, stream>>>(kb, Wk, bk, Kpb, DD, DD, 0);
        sgemm_nn<<<gp, blk, 0, stream>>>(vb, Wv, bv, Vpb, DD, DD, 1);

        // Scores: Sb = Qp[b] @ Kpb^T + mask[b][col]
        sgemm_nt_mask<<<gs, blk, 0, stream>>>(Qpb, Kpb, mb, Sb, DD, SKL);

        // Softmax rows
        softmax_rows<<<dim3(SQL), blk, 0, stream>>>(Sb, SKL);

        // out[b] = Sb @ Vpb   (overwrites Qp[b] — already consumed)
        sgemm_nn<<<gv, blk, 0, stream>>>(Sb, Vpb, nullptr, outb, DD, SKL, 0);
    }
}

// Round 3
// 1094.049 us; speedup vs baseline: 6.1431x; 6.1431x over previous
//
#include <hip/hip_runtime.h>
#include <math.h>

// Problem constants
#define BB 8
#define SQL 2048
#define SKL 2048
#define DD 1024

typedef __attribute__((ext_vector_type(8))) short bf16x8;
typedef __attribute__((ext_vector_type(4))) float f32x4;

// ---- bf16 split helpers (round-to-nearest) ----
__device__ __forceinline__ unsigned short f2bf(float f) {
    unsigned u = __float_as_uint(f);
    u += 0x7fffu + ((u >> 16) & 1u);
    return (unsigned short)(u >> 16);
}
__device__ __forceinline__ float bf2f(unsigned short h) {
    return __uint_as_float((unsigned)h << 16);
}
// pack (hi,lo) pair: low short = hi (lives at even k'), high short = lo (odd k')
__device__ __forceinline__ unsigned packsplit(float a) {
    unsigned short h = f2bf(a);
    unsigned short l = f2bf(a - bf2f(h));
    return ((unsigned)l << 16) | (unsigned)h;
}

// ---- elementwise fp32 -> split-pair bf16 (interleaved along last dim) ----
__global__ __launch_bounds__(256)
void split2(const float* __restrict__ in, unsigned* __restrict__ out, long n4) {
    long i = (long)blockIdx.x * 256 + threadIdx.x;
    if (i >= n4) return;
    float4 v = ((const float4*)in)[i];
    uint4 o;
    o.x = packsplit(v.x); o.y = packsplit(v.y);
    o.z = packsplit(v.z); o.w = packsplit(v.w);
    ((uint4*)out)[i] = o;
}

// ---- W [K=1024][N=1024] fp32 -> Wt [N][2K] split pairs (transpose + split) ----
__global__ __launch_bounds__(256)
void splitT(const float* __restrict__ W, unsigned* __restrict__ Wt) {
    __shared__ float t[32][33];
    const int n0 = blockIdx.x * 32, k0 = blockIdx.y * 32;
    const int tx = threadIdx.x & 31, ty = threadIdx.x >> 5;
#pragma unroll
    for (int r = 0; r < 32; r += 8)
        t[ty + r][tx] = W[(long)(k0 + ty + r) * DD + n0 + tx];   // t[k][n]
    __syncthreads();
#pragma unroll
    for (int r = 0; r < 32; r += 8)
        Wt[(long)(n0 + ty + r) * DD + k0 + tx] = packsplit(t[tx][ty + r]);
}

// ---- u32-element transpose: in [SKL][DD] -> out [DD][SKL] (pairs move intact) ----
__global__ __launch_bounds__(256)
void transpose_u32(const unsigned* __restrict__ in, unsigned* __restrict__ out,
                   long sIn, long sOut) {
    __shared__ unsigned t[32][33];
    const unsigned* ib = in + (long)blockIdx.z * sIn;
    unsigned* ob = out + (long)blockIdx.z * sOut;
    const int c0 = blockIdx.x * 32;   // col of in (0..DD)
    const int r0 = blockIdx.y * 32;   // row of in (0..SKL)
    const int tx = threadIdx.x & 31, ty = threadIdx.x >> 5;
#pragma unroll
    for (int r = 0; r < 32; r += 8)
        t[ty + r][tx] = ib[(long)(r0 + ty + r) * DD + c0 + tx];
    __syncthreads();
#pragma unroll
    for (int r = 0; r < 32; r += 8)
        ob[(long)(c0 + ty + r) * SKL + r0 + tx] = t[tx][ty + r];
}

// ---- split-bf16 NT GEMM: C[m,n] = sum_k a[m,k]*b[n,k], exact via 2 MFMAs ----
// A,B: bf16 rows of length Kv (virtual K = 2*real K, hi/lo interleaved), contiguous.
// mode 0: Cf = acc                      (fp32 out)
// mode 1: Cu = packsplit(acc + bias[n]) (split out)
// mode 2: Cu = packsplit(tanh(acc + bias[n]))
// mode 3: Cf = acc + (float)mask[n]     (fp32 out)
__global__ __launch_bounds__(256, 2)
void gemm_nt2(const unsigned short* __restrict__ A,
              const unsigned short* __restrict__ B,
              const float* __restrict__ bias,
              const int* __restrict__ mask,
              float* __restrict__ Cf, unsigned* __restrict__ Cu,
              int Kv, int Nc, long sA, long sB, long sC, int sM, int mode)
{
    __shared__ unsigned short As[128 * 32];
    __shared__ unsigned short Bs[128 * 32];

    const int z = blockIdx.z;
    A += (long)z * sA;
    B += (long)z * sB;

    const int tid = threadIdx.x;
    const int lane = tid & 63;
    const int wave = tid >> 6;
    const int wm = (wave & 1) * 64;
    const int wn = (wave >> 1) * 64;
    const int l15 = lane & 15, lq = lane >> 4;

    const long row0 = (long)blockIdx.y * 128;
    const long col0 = (long)blockIdx.x * 128;

    // staging: chunk c = tid + i*256 -> row c>>2, k-seg (c&3)*8 ; lds = c*16B
    const int srow = tid >> 2;
    const int sseg = (tid & 3) * 8;
    const unsigned short* Ag = A + (row0 + srow) * (long)Kv + sseg;
    const unsigned short* Bg = B + (col0 + srow) * (long)Kv + sseg;
    const long rstep = (long)64 * Kv;

    f32x4 acc[4][4];
#pragma unroll
    for (int i = 0; i < 4; i++)
#pragma unroll
        for (int j = 0; j < 4; j++)
#pragma unroll
            for (int e = 0; e < 4; e++) acc[i][j][e] = 0.f;

    for (int k0 = 0; k0 < Kv; k0 += 32) {
#pragma unroll
        for (int i = 0; i < 2; i++) {
            __builtin_amdgcn_global_load_lds(
                (const __attribute__((address_space(1))) void*)(Ag + i * rstep + k0),
                (__attribute__((address_space(3))) void*)(As + (tid + i * 256) * 8),
                16, 0, 0);
            __builtin_amdgcn_global_load_lds(
                (const __attribute__((address_space(1))) void*)(Bg + i * rstep + k0),
                (__attribute__((address_space(3))) void*)(Bs + (tid + i * 256) * 8),
                16, 0, 0);
        }
        __syncthreads();

        bf16x8 af[4], bfr[4], bsw[4];
#pragma unroll
        for (int i = 0; i < 4; i++) {
            af[i]  = *(const bf16x8*)(As + (wm + i * 16 + l15) * 32 + lq * 8);
            bfr[i] = *(const bf16x8*)(Bs + (wn + i * 16 + l15) * 32 + lq * 8);
        }
#pragma unroll
        for (int j = 0; j < 4; j++) {
            bf16x8 t = bfr[j], s;
            s[0] = t[1]; s[1] = t[0]; s[2] = t[3]; s[3] = t[2];
            s[4] = t[5]; s[5] = t[4]; s[6] = t[7]; s[7] = t[6];
            bsw[j] = s;
        }
#pragma unroll
        for (int i = 0; i < 4; i++)
#pragma unroll
            for (int j = 0; j < 4; j++) {
                acc[i][j] = __builtin_amdgcn_mfma_f32_16x16x32_bf16(af[i], bfr[j], acc[i][j], 0, 0, 0);
                acc[i][j] = __builtin_amdgcn_mfma_f32_16x16x32_bf16(af[i], bsw[j], acc[i][j], 0, 0, 0);
            }
        __syncthreads();
    }

    // epilogue; C/D layout: col = lane&15, row = (lane>>4)*4 + reg  [m89]
    const long zc = (long)z * sC;
    if (mode == 0 || mode == 3) {
#pragma unroll
        for (int i = 0; i < 4; i++) {
#pragma unroll
            for (int j = 0; j < 4; j++) {
                const long c = col0 + wn + j * 16 + l15;
                const float madd = (mode == 3) ? (float)mask[(long)z * sM + c] : 0.f;
                const long rbase = row0 + wm + i * 16 + lq * 4;
#pragma unroll
                for (int r = 0; r < 4; r++)
                    Cf[zc + (rbase + r) * (long)Nc + c] = acc[i][j][r] + madd;
            }
        }
    } else {
#pragma unroll
        for (int i = 0; i < 4; i++) {
#pragma unroll
            for (int j = 0; j < 4; j++) {
                const long c = col0 + wn + j * 16 + l15;
                const float bv = bias[c];
                const long rbase = row0 + wm + i * 16 + lq * 4;
#pragma unroll
                for (int r = 0; r < 4; r++) {
                    float val = acc[i][j][r] + bv;
                    if (mode == 2) val = tanhf(val);
                    Cu[zc + (rbase + r) * (long)Nc + c] = packsplit(val);
                }
            }
        }
    }
}

// ---- row softmax fp32 [SKL] -> split pairs (in place; same bytes) ----
__global__ __launch_bounds__(256)
void softmax2(float* __restrict__ S, unsigned* __restrict__ P) {
    float* p = S + (long)blockIdx.x * SKL;
    unsigned* qo = P + (long)blockIdx.x * SKL;
    const int tid = threadIdx.x;
    const int w = tid >> 6, lane = tid & 63;

    float4 v0 = *(float4*)(p + tid * 8);
    float4 v1 = *(float4*)(p + tid * 8 + 4);

    float m = fmaxf(fmaxf(fmaxf(v0.x, v0.y), fmaxf(v0.z, v0.w)),
                    fmaxf(fmaxf(v1.x, v1.y), fmaxf(v1.z, v1.w)));
#pragma unroll
    for (int off = 32; off; off >>= 1) m = fmaxf(m, __shfl_down(m, off));

    __shared__ float wm_[4], ws_[4];
    if (lane == 0) wm_[w] = m;
    __syncthreads();
    const float bm = fmaxf(fmaxf(wm_[0], wm_[1]), fmaxf(wm_[2], wm_[3]));

    v0.x = __expf(v0.x - bm); v0.y = __expf(v0.y - bm);
    v0.z = __expf(v0.z - bm); v0.w = __expf(v0.w - bm);
    v1.x = __expf(v1.x - bm); v1.y = __expf(v1.y - bm);
    v1.z = __expf(v1.z - bm); v1.w = __expf(v1.w - bm);

    float s = v0.x + v0.y + v0.z + v0.w + v1.x + v1.y + v1.z + v1.w;
#pragma unroll
    for (int off = 32; off; off >>= 1) s += __shfl_down(s, off);
    if (lane == 0) ws_[w] = s;
    __syncthreads();
    const float inv = 1.f / (ws_[0] + ws_[1] + ws_[2] + ws_[3]);

    uint4 o0, o1;
    o0.x = packsplit(v0.x * inv); o0.y = packsplit(v0.y * inv);
    o0.z = packsplit(v0.z * inv); o0.w = packsplit(v0.w * inv);
    o1.x = packsplit(v1.x * inv); o1.y = packsplit(v1.y * inv);
    o1.z = packsplit(v1.z * inv); o1.w = packsplit(v1.w * inv);
    *(uint4*)(qo + tid * 8)     = o0;
    *(uint4*)(qo + tid * 8 + 4) = o1;
}

extern "C" void kernel_launch(void* const* d_in, const int* in_sizes, int n_in,
                              void* d_out, int out_size, void* d_ws, size_t ws_size,
                              hipStream_t stream)
{
    const float* q  = (const float*)d_in[0];
    const float* k  = (const float*)d_in[1];
    const float* v  = (const float*)d_in[2];
    const int* mask = (const int*)d_in[3];
    const float* Wq = (const float*)d_in[4];
    const float* bq = (const float*)d_in[5];
    const float* Wk = (const float*)d_in[6];
    const float* bk = (const float*)d_in[7];
    const float* Wv = (const float*)d_in[8];
    const float* bv = (const float*)d_in[9];
    float* out = (float*)d_out;

    // per-batch workspace: in2 (8.39MB) + Kp2 (8.39MB) + S (16.78MB) = 33.55MB
    const size_t GRP = 33554432ULL;
    const int G = (ws_size >= 8 * GRP) ? 8 : (ws_size >= 4 * GRP) ? 4
                : (ws_size >= 2 * GRP) ? 2 : 1;

    const long perB = (long)SQL * DD;   // elements per batch of q/out

    for (int g0 = 0; g0 < BB; g0 += G) {
        unsigned* in2   = (unsigned*)d_ws;                   // [G][2048][1024] u32
        unsigned* Kp2   = in2 + (long)G * SKL * DD;          // [G][2048][1024] u32
        float*    S     = (float*)(Kp2 + (long)G * SKL * DD);// [G][2048][2048] f32
        unsigned* Su    = (unsigned*)S;
        unsigned* Vp2   = Su;                                // lower half of S (dead before QK^T)
        unsigned* Wslot = Su + (long)G * SQL * DD;           // upper part of S
        unsigned* Vpt2  = in2;                               // reuse after V proj
        unsigned* Qp2   = (unsigned*)(out + (long)g0 * perB);// Qp lives in d_out

        const long n4 = (long)G * perB / 4;
        const dim3 b256(256);
        const dim3 gSplit((unsigned)(n4 / 256));
        const dim3 gW(32, 32);
        const dim3 gProj(8, 16, G);
        const dim3 gQK(16, 16, G);
        const dim3 gPV(8, 16, G);
        const dim3 gT(DD / 32, SKL / 32, G);
        const dim3 gSm(G * SQL);

        // --- Q projection -> Qp2 (in d_out) ---
        splitT<<<gW, b256, 0, stream>>>(Wq, Wslot);
        split2<<<gSplit, b256, 0, stream>>>(q + (long)g0 * perB, in2, n4);
        gemm_nt2<<<gProj, b256, 0, stream>>>((const unsigned short*)in2,
            (const unsigned short*)Wslot, bq, nullptr, nullptr, Qp2,
            2 * DD, DD, (long)SQL * 2 * DD, 0, (long)SQL * DD, 0, 1);
        // --- K projection -> Kp2 ---
        splitT<<<gW, b256, 0, stream>>>(Wk, Wslot);
        split2<<<gSplit, b256, 0, stream>>>(k + (long)g0 * perB, in2, n4);
        gemm_nt2<<<gProj, b256, 0, stream>>>((const unsigned short*)in2,
            (const unsigned short*)Wslot, bk, nullptr, nullptr, Kp2,
            2 * DD, DD, (long)SKL * 2 * DD, 0, (long)SKL * DD, 0, 1);
        // --- V projection (+tanh) -> Vp2 (lower S) ---
        splitT<<<gW, b256, 0, stream>>>(Wv, Wslot);
        split2<<<gSplit, b256, 0, stream>>>(v + (long)g0 * perB, in2, n4);
        gemm_nt2<<<gProj, b256, 0, stream>>>((const unsigned short*)in2,
            (const unsigned short*)Wslot, bv, nullptr, nullptr, Vp2,
            2 * DD, DD, (long)SKL * 2 * DD, 0, (long)SKL * DD, 0, 2);
        // --- transpose Vp2 -> Vpt2 (in2; in2 dead) ---
        transpose_u32<<<gT, b256, 0, stream>>>(Vp2, Vpt2, (long)SKL * DD, (long)SKL * DD);
        // --- QK^T + mask -> S (overwrites Vp2/Wslot, both dead) ---
        gemm_nt2<<<gQK, b256, 0, stream>>>((const unsigned short*)Qp2,
            (const unsigned short*)Kp2, nullptr, mask + (long)g0 * SKL, S, nullptr,
            2 * DD, SKL, (long)SQL * 2 * DD, (long)SKL * 2 * DD, (long)SQL * SKL, SKL, 3);
        // --- softmax rows, write split pairs in place ---
        softmax2<<<gSm, b256, 0, stream>>>(S, Su);
        // --- PV -> out (Qp2 dead) ---
        gemm_nt2<<<gPV, b256, 0, stream>>>((const unsigned short*)Su,
            (const unsigned short*)Vpt2, nullptr, nullptr,
            out + (long)g0 * perB, nullptr,
            2 * SKL, DD, (long)SQL * 2 * SKL, (long)DD * 2 * SKL, (long)SQL * DD, 0, 0);
    }
}

// Round 4
// 989.566 us; speedup vs baseline: 6.7917x; 1.1056x over previous
//
#include <hip/hip_runtime.h>
#include <math.h>

#define BB 8
#define SQL 2048
#define SKL 2048
#define DD 1024

typedef __attribute__((ext_vector_type(8))) short bf16x8;
typedef __attribute__((ext_vector_type(4))) float f32x4;
typedef __attribute__((ext_vector_type(4))) unsigned short us4;
typedef unsigned short u16;

__device__ __forceinline__ u16 f2bf(float f) {
    unsigned u = __float_as_uint(f);
    u += 0x7fffu + ((u >> 16) & 1u);
    return (u16)(u >> 16);
}
__device__ __forceinline__ float bf2f(u16 h) {
    return __uint_as_float((unsigned)h << 16);
}

// ---- fp32 -> hi/lo bf16 planes ----
__global__ __launch_bounds__(256)
void split3(const float* __restrict__ in, u16* __restrict__ oh,
            u16* __restrict__ ol, long n4) {
    long i = (long)blockIdx.x * 256 + threadIdx.x;
    if (i >= n4) return;
    float4 v = ((const float4*)in)[i];
    us4 h, l;
    h.x = f2bf(v.x); l.x = f2bf(v.x - bf2f(h.x));
    h.y = f2bf(v.y); l.y = f2bf(v.y - bf2f(h.y));
    h.z = f2bf(v.z); l.z = f2bf(v.z - bf2f(h.z));
    h.w = f2bf(v.w); l.w = f2bf(v.w - bf2f(h.w));
    ((us4*)oh)[i] = h;
    ((us4*)ol)[i] = l;
}

// ---- W [K][N] fp32 -> WhT/WlT [N][K] bf16 planes (transpose + split) ----
__global__ __launch_bounds__(256)
void splitT3(const float* __restrict__ W, u16* __restrict__ WhT,
             u16* __restrict__ WlT) {
    __shared__ float t[32][33];
    const int n0 = blockIdx.x * 32, k0 = blockIdx.y * 32;
    const int tx = threadIdx.x & 31, ty = threadIdx.x >> 5;
#pragma unroll
    for (int r = 0; r < 32; r += 8)
        t[ty + r][tx] = W[(long)(k0 + ty + r) * DD + n0 + tx];
    __syncthreads();
#pragma unroll
    for (int r = 0; r < 32; r += 8) {
        float x = t[tx][ty + r];
        u16 h = f2bf(x);
        WhT[(long)(n0 + ty + r) * DD + k0 + tx] = h;
        WlT[(long)(n0 + ty + r) * DD + k0 + tx] = f2bf(x - bf2f(h));
    }
}

#define GLL(gp, lp) __builtin_amdgcn_global_load_lds( \
    (const __attribute__((address_space(1))) void*)(gp), \
    (__attribute__((address_space(3))) void*)(lp), 16, 0, 0)

// ---- 3-term split-bf16 NT GEMM: C = A·B^T (exact to ~2^-16) ----
// mode 0: Cf = acc ; mode 3: Cf = acc + mask[col]
// mode 1: C1/C2 = split(acc + bias[col])
// mode 2: C1[col*ldc + row] = bf16(tanh(acc + bias[col]))  (transposed out)
__global__ __launch_bounds__(256, 2)
void gemm3(const u16* __restrict__ Ah, const u16* __restrict__ Al,
           const u16* __restrict__ Bh, const u16* __restrict__ Bl,
           int lda, int ldb, int K, long sA, long sB,
           const float* __restrict__ bias, const int* __restrict__ mask, int sM,
           float* __restrict__ Cf, u16* __restrict__ C1, u16* __restrict__ C2,
           long sC, int ldc, int mode)
{
    __shared__ u16 AsH[4096], AsL[4096], BsH[4096], BsL[4096];

    const int z = blockIdx.z;
    const long zA = (long)z * sA, zB = (long)z * sB;
    const int tid = threadIdx.x, lane = tid & 63, wave = tid >> 6;
    const int wm = (wave & 1) * 64, wn = (wave >> 1) * 64;
    const int l15 = lane & 15, lq = lane >> 4;
    const long row0 = (long)blockIdx.y * 128, col0 = (long)blockIdx.x * 128;

    // staging map: chunk c -> LDS row c>>2, quarter c&3; global quarter XOR-swizzled
    long offA[2], offB[2]; int lds[2];
#pragma unroll
    for (int it = 0; it < 2; it++) {
        int c = tid + it * 256, row = c >> 2;
        int qg = (c & 3) ^ ((row >> 1) & 3);
        offA[it] = (row0 + row) * (long)lda + qg * 8;
        offB[it] = (col0 + row) * (long)ldb + qg * 8;
        lds[it] = c * 8;
    }

    // fragment LDS offsets (swizzled reads)
    int aoff[4], boff[4];
#pragma unroll
    for (int i = 0; i < 4; i++) {
        int r = wm + i * 16 + l15;
        aoff[i] = r * 32 + ((lq ^ ((r >> 1) & 3)) * 8);
    }
#pragma unroll
    for (int j = 0; j < 4; j++) {
        int r = wn + j * 16 + l15;
        boff[j] = r * 32 + ((lq ^ ((r >> 1) & 3)) * 8);
    }

    f32x4 acc[4][4];
#pragma unroll
    for (int i = 0; i < 4; i++)
#pragma unroll
        for (int j = 0; j < 4; j++)
#pragma unroll
            for (int e = 0; e < 4; e++) acc[i][j][e] = 0.f;

    for (int k0 = 0; k0 < K; k0 += 32) {
#pragma unroll
        for (int it = 0; it < 2; it++) {
            GLL(Ah + zA + offA[it] + k0, AsH + lds[it]);
            GLL(Al + zA + offA[it] + k0, AsL + lds[it]);
            GLL(Bh + zB + offB[it] + k0, BsH + lds[it]);
            GLL(Bl + zB + offB[it] + k0, BsL + lds[it]);
        }
        __syncthreads();

        bf16x8 ah[4], al[4], bh[4], bl[4];
#pragma unroll
        for (int i = 0; i < 4; i++) {
            ah[i] = *(const bf16x8*)(AsH + aoff[i]);
            al[i] = *(const bf16x8*)(AsL + aoff[i]);
        }
#pragma unroll
        for (int j = 0; j < 4; j++) {
            bh[j] = *(const bf16x8*)(BsH + boff[j]);
            bl[j] = *(const bf16x8*)(BsL + boff[j]);
        }
#pragma unroll
        for (int i = 0; i < 4; i++)
#pragma unroll
            for (int j = 0; j < 4; j++) {
                acc[i][j] = __builtin_amdgcn_mfma_f32_16x16x32_bf16(ah[i], bh[j], acc[i][j], 0, 0, 0);
                acc[i][j] = __builtin_amdgcn_mfma_f32_16x16x32_bf16(ah[i], bl[j], acc[i][j], 0, 0, 0);
                acc[i][j] = __builtin_amdgcn_mfma_f32_16x16x32_bf16(al[i], bh[j], acc[i][j], 0, 0, 0);
            }
        __syncthreads();
    }

    const long zc = (long)z * sC;
#pragma unroll
    for (int i = 0; i < 4; i++) {
#pragma unroll
        for (int j = 0; j < 4; j++) {
            const long col = col0 + wn + j * 16 + l15;
            const long rbase = row0 + wm + i * 16 + lq * 4;
            if (mode == 0 || mode == 3) {
                const float madd = (mode == 3) ? (float)mask[(long)z * sM + col] : 0.f;
#pragma unroll
                for (int r = 0; r < 4; r++)
                    Cf[zc + (rbase + r) * (long)ldc + col] = acc[i][j][r] + madd;
            } else if (mode == 1) {
                const float bv = bias[col];
#pragma unroll
                for (int r = 0; r < 4; r++) {
                    float val = acc[i][j][r] + bv;
                    u16 h = f2bf(val);
                    C1[zc + (rbase + r) * (long)ldc + col] = h;
                    C2[zc + (rbase + r) * (long)ldc + col] = f2bf(val - bf2f(h));
                }
            } else {  // mode 2: transposed tanh bf16
                const float bv = bias[col];
                us4 o;
                o.x = f2bf(tanhf(acc[i][j][0] + bv));
                o.y = f2bf(tanhf(acc[i][j][1] + bv));
                o.z = f2bf(tanhf(acc[i][j][2] + bv));
                o.w = f2bf(tanhf(acc[i][j][3] + bv));
                *(us4*)(C1 + zc + col * (long)ldc + rbase) = o;
            }
        }
    }
}

// ---- plain bf16 NT GEMM (1 MFMA per tile-chunk), fp32 out ----
__global__ __launch_bounds__(256, 2)
void gemm1(const u16* __restrict__ A, const u16* __restrict__ B,
           float* __restrict__ C, int lda, int ldb, int K,
           long sA, long sB, long sC, int ldc)
{
    __shared__ u16 As[4096], Bs[4096];

    const int z = blockIdx.z;
    const long zA = (long)z * sA, zB = (long)z * sB;
    const int tid = threadIdx.x, lane = tid & 63, wave = tid >> 6;
    const int wm = (wave & 1) * 64, wn = (wave >> 1) * 64;
    const int l15 = lane & 15, lq = lane >> 4;
    const long row0 = (long)blockIdx.y * 128, col0 = (long)blockIdx.x * 128;

    long offA[2], offB[2]; int lds[2];
#pragma unroll
    for (int it = 0; it < 2; it++) {
        int c = tid + it * 256, row = c >> 2;
        int qg = (c & 3) ^ ((row >> 1) & 3);
        offA[it] = (row0 + row) * (long)lda + qg * 8;
        offB[it] = (col0 + row) * (long)ldb + qg * 8;
        lds[it] = c * 8;
    }
    int aoff[4], boff[4];
#pragma unroll
    for (int i = 0; i < 4; i++) {
        int r = wm + i * 16 + l15;
        aoff[i] = r * 32 + ((lq ^ ((r >> 1) & 3)) * 8);
    }
#pragma unroll
    for (int j = 0; j < 4; j++) {
        int r = wn + j * 16 + l15;
        boff[j] = r * 32 + ((lq ^ ((r >> 1) & 3)) * 8);
    }

    f32x4 acc[4][4];
#pragma unroll
    for (int i = 0; i < 4; i++)
#pragma unroll
        for (int j = 0; j < 4; j++)
#pragma unroll
            for (int e = 0; e < 4; e++) acc[i][j][e] = 0.f;

    for (int k0 = 0; k0 < K; k0 += 32) {
#pragma unroll
        for (int it = 0; it < 2; it++) {
            GLL(A + zA + offA[it] + k0, As + lds[it]);
            GLL(B + zB + offB[it] + k0, Bs + lds[it]);
        }
        __syncthreads();
        bf16x8 af[4], bf[4];
#pragma unroll
        for (int i = 0; i < 4; i++) af[i] = *(const bf16x8*)(As + aoff[i]);
#pragma unroll
        for (int j = 0; j < 4; j++) bf[j] = *(const bf16x8*)(Bs + boff[j]);
#pragma unroll
        for (int i = 0; i < 4; i++)
#pragma unroll
            for (int j = 0; j < 4; j++)
                acc[i][j] = __builtin_amdgcn_mfma_f32_16x16x32_bf16(af[i], bf[j], acc[i][j], 0, 0, 0);
        __syncthreads();
    }

    const long zc = (long)z * sC;
#pragma unroll
    for (int i = 0; i < 4; i++)
#pragma unroll
        for (int j = 0; j < 4; j++) {
            const long col = col0 + wn + j * 16 + l15;
            const long rbase = row0 + wm + i * 16 + lq * 4;
#pragma unroll
            for (int r = 0; r < 4; r++)
                C[zc + (rbase + r) * (long)ldc + col] = acc[i][j][r];
        }
}

// ---- row softmax: fp32 row [2048] -> bf16 row in place (row stride 4096 u16) ----
__global__ __launch_bounds__(256)
void softmax_bf(float* __restrict__ S)
{
    float* p = S + (long)blockIdx.x * SKL;
    u16* po = (u16*)S + (long)blockIdx.x * 2 * SKL;
    const int tid = threadIdx.x;
    const int w = tid >> 6, lane = tid & 63;

    float4 v0 = *(float4*)(p + tid * 8);
    float4 v1 = *(float4*)(p + tid * 8 + 4);

    float m = fmaxf(fmaxf(fmaxf(v0.x, v0.y), fmaxf(v0.z, v0.w)),
                    fmaxf(fmaxf(v1.x, v1.y), fmaxf(v1.z, v1.w)));
#pragma unroll
    for (int off = 32; off; off >>= 1) m = fmaxf(m, __shfl_down(m, off));

    __shared__ float wm_[4], ws_[4];
    if (lane == 0) wm_[w] = m;
    __syncthreads();
    const float bm = fmaxf(fmaxf(wm_[0], wm_[1]), fmaxf(wm_[2], wm_[3]));

    v0.x = __expf(v0.x - bm); v0.y = __expf(v0.y - bm);
    v0.z = __expf(v0.z - bm); v0.w = __expf(v0.w - bm);
    v1.x = __expf(v1.x - bm); v1.y = __expf(v1.y - bm);
    v1.z = __expf(v1.z - bm); v1.w = __expf(v1.w - bm);

    float s = v0.x + v0.y + v0.z + v0.w + v1.x + v1.y + v1.z + v1.w;
#pragma unroll
    for (int off = 32; off; off >>= 1) s += __shfl_down(s, off);
    if (lane == 0) ws_[w] = s;
    __syncthreads();
    const float inv = 1.f / (ws_[0] + ws_[1] + ws_[2] + ws_[3]);

    us4 o0, o1;
    o0.x = f2bf(v0.x * inv); o0.y = f2bf(v0.y * inv);
    o0.z = f2bf(v0.z * inv); o0.w = f2bf(v0.w * inv);
    o1.x = f2bf(v1.x * inv); o1.y = f2bf(v1.y * inv);
    o1.z = f2bf(v1.z * inv); o1.w = f2bf(v1.w * inv);
    *(us4*)(po + tid * 8) = o0;
    *(us4*)(po + tid * 8 + 4) = o1;
}

extern "C" void kernel_launch(void* const* d_in, const int* in_sizes, int n_in,
                              void* d_out, int out_size, void* d_ws, size_t ws_size,
                              hipStream_t stream)
{
    const float* q  = (const float*)d_in[0];
    const float* k  = (const float*)d_in[1];
    const float* v  = (const float*)d_in[2];
    const int* mask = (const int*)d_in[3];
    const float* Wq = (const float*)d_in[4];
    const float* bq = (const float*)d_in[5];
    const float* Wk = (const float*)d_in[6];
    const float* bk = (const float*)d_in[7];
    const float* Wv = (const float*)d_in[8];
    const float* bv = (const float*)d_in[9];
    float* out = (float*)d_out;

    const long PZ = (long)SKL * DD;      // 2M elems per z per plane
    // ws layout (bytes): KpH 33.55M | KpL 33.55M | Vt 33.55M | S 134.2M = 234.9M
    u16*   KpH = (u16*)d_ws;
    u16*   KpL = KpH + BB * PZ;
    u16*   Vt  = KpL + BB * PZ;                 // [8][1024][2048]
    float* S   = (float*)(Vt + BB * PZ);        // [8][2048][2048] fp32
    // aliases inside S (dead before QK^T writes S):
    u16*   inH = (u16*)S;                       // [8][2048][1024]
    u16*   inL = inH + BB * PZ;
    u16*   WhT = inL + BB * PZ;                 // [1024][1024]
    u16*   WlT = WhT + (long)DD * DD;
    // Qp planes live in d_out (64 MB <= 67 MB); consumed by QK before PV writes out
    u16*   QpH = (u16*)d_out;
    u16*   QpL = QpH + BB * PZ;
    u16*   P   = (u16*)S;                       // softmax in place, row stride 4096

    const dim3 b256(256);
    const long n4 = BB * PZ / 4;
    const dim3 gSplit((unsigned)(n4 / 256));
    const dim3 gW(32, 32);
    const dim3 gProj(8, 16, BB);
    const dim3 gQK(16, 16, BB);
    const dim3 gPV(8, 16, BB);
    const dim3 gSm(BB * SQL);

    // --- Q projection -> Qp planes (d_out) ---
    split3<<<gSplit, b256, 0, stream>>>(q, inH, inL, n4);
    splitT3<<<gW, b256, 0, stream>>>(Wq, WhT, WlT);
    gemm3<<<gProj, b256, 0, stream>>>(inH, inL, WhT, WlT, DD, DD, DD, PZ, 0,
                                      bq, nullptr, 0, nullptr, QpH, QpL, PZ, DD, 1);
    // --- K projection -> Kp planes ---
    split3<<<gSplit, b256, 0, stream>>>(k, inH, inL, n4);
    splitT3<<<gW, b256, 0, stream>>>(Wk, WhT, WlT);
    gemm3<<<gProj, b256, 0, stream>>>(inH, inL, WhT, WlT, DD, DD, DD, PZ, 0,
                                      bk, nullptr, 0, nullptr, KpH, KpL, PZ, DD, 1);
    // --- V projection -> Vt transposed bf16 (+tanh) ---
    split3<<<gSplit, b256, 0, stream>>>(v, inH, inL, n4);
    splitT3<<<gW, b256, 0, stream>>>(Wv, WhT, WlT);
    gemm3<<<gProj, b256, 0, stream>>>(inH, inL, WhT, WlT, DD, DD, DD, PZ, 0,
                                      bv, nullptr, 0, nullptr, Vt, nullptr, PZ, SKL, 2);
    // --- QK^T + mask -> S fp32 (overwrites in/W aliases, both dead) ---
    gemm3<<<gQK, b256, 0, stream>>>(QpH, QpL, KpH, KpL, DD, DD, DD, PZ, PZ,
                                    nullptr, mask, SKL,
                                    S, nullptr, nullptr, (long)SQL * SKL, SKL, 3);
    // --- softmax rows -> bf16 in place ---
    softmax_bf<<<gSm, b256, 0, stream>>>(S);
    // --- PV (plain bf16) -> out ---
    gemm1<<<gPV, b256, 0, stream>>>(P, Vt, out, 2 * SKL, SKL, SKL,
                                    (long)SQL * 2 * SKL, PZ,
                                    (long)SQL * DD, DD);
}